// Round 5
// baseline (1156.280 us; speedup 1.0000x reference)
//
#include <hip/hip_runtime.h>
#include <cstdint>
#include <math.h>

typedef _Float16 f16;
typedef __attribute__((ext_vector_type(4))) _Float16 f16x4;
typedef __attribute__((ext_vector_type(8))) _Float16 f16x8;
typedef __attribute__((ext_vector_type(4))) float f32x4;

// ---------------------------------------------------------------- helpers
__device__ inline void gload_lds16(const void* g, void* l) {
  auto gp = reinterpret_cast<const __attribute__((address_space(1))) uint32_t*>(
      reinterpret_cast<uintptr_t>(g));
  auto lp = reinterpret_cast<__attribute__((address_space(3))) uint32_t*>(
      reinterpret_cast<uintptr_t>(l));
  __builtin_amdgcn_global_load_lds(gp, lp, 16 /*bytes*/, 0, 0);
}

__device__ inline float wave_sum64(float v) {
#pragma unroll
  for (int m = 1; m < 64; m <<= 1) v += __shfl_xor(v, m);
  return v;
}

// ---------------------------------------------------------------- fp32 -> f16 convert
__global__ __launch_bounds__(256) void cvt_kernel(const float* __restrict__ src,
                                                  f16* __restrict__ dst, int n4) {
  int idx = blockIdx.x * blockDim.x + threadIdx.x;
  int stride = gridDim.x * blockDim.x;
  for (int i = idx; i < n4; i += stride) {
    float4 v = reinterpret_cast<const float4*>(src)[i];
    f16x4 h;
    h.x = (f16)v.x; h.y = (f16)v.y; h.z = (f16)v.z; h.w = (f16)v.w;
    reinterpret_cast<f16x4*>(dst)[i] = h;
  }
}

// ---------------------------------------------------------------- GEMM  C[M][N] = A[M][K] * B[N][K]^T
// 128x128 tile, BK=32, 4 waves (each a 64x64 quadrant), m97 structure + XCD swizzle.
// EPI==0: plain fp32 C.  EPI==1: fused RMS-norm (per 128-col head row) -> f16 Ch,
// with attention scale * log2e folded (Q path).
template <bool MB, int EPI>
__global__ __launch_bounds__(256, 2) void gemm_bt_f16(const f16* __restrict__ A,
                                                      const f16* __restrict__ Bw,
                                                      float* __restrict__ C,
                                                      f16* __restrict__ Ch,
                                                      const float* __restrict__ wvec,
                                                      int M, int N, int K) {
  __shared__ f16 As[2][128][32];
  __shared__ f16 Bs[2][128][32];
  const int tid = threadIdx.x;
  const int l = tid & 63, w = tid >> 6;
  const int lq = l & 15, lk = l >> 4;
  const int wr = w >> 1, wc = w & 1;
  // XCD-aware bijective swizzle (nwg % 8 == 0 for all our grids)
  const int nwg = gridDim.x * gridDim.y;
  const int p = blockIdx.y * gridDim.x + blockIdx.x;
  const int L = (p & 7) * (nwg >> 3) + (p >> 3);
  const int bx = L % gridDim.x, by = L / gridDim.x;
  const int brow = by * 128, bcol = bx * 128;
  const int srow = w * 16 + (l >> 2);   // staging row (+j*64)
  const int scol = (l & 3) * 8;         // staging col in f16 elems
  const int KT = K >> 5;

  f32x4 acc[4][4];
  f32x4 zf = {0.f, 0.f, 0.f, 0.f};
#pragma unroll
  for (int m = 0; m < 4; ++m)
#pragma unroll
    for (int n = 0; n < 4; ++n) acc[m][n] = zf;

  auto stage = [&](int kt, int buf) {
    const int k0 = kt * 32 + scol;
#pragma unroll
    for (int j = 0; j < 2; ++j) {
      int ra = brow + j * 64 + srow;
      if (MB) ra = (ra < M) ? ra : (M - 1);
      gload_lds16(A + (size_t)ra * K + k0,
                  (char*)(&As[buf][0][0]) + j * 4096 + w * 1024);
      int rb = bcol + j * 64 + srow;
      gload_lds16(Bw + (size_t)rb * K + k0,
                  (char*)(&Bs[buf][0][0]) + j * 4096 + w * 1024);
    }
  };

  stage(0, 0);
  for (int kt = 0; kt < KT; ++kt) {
    const int buf = kt & 1;
    __syncthreads();                 // drains vmcnt for stage(kt); also read/overwrite fence
    if (kt + 1 < KT) stage(kt + 1, buf ^ 1);  // prefetch overlaps this iter's compute
    f16x8 af[4], bf[4];
#pragma unroll
    for (int m = 0; m < 4; ++m)
      af[m] = *reinterpret_cast<const f16x8*>(&As[buf][wr * 64 + m * 16 + lq][lk * 8]);
#pragma unroll
    for (int n = 0; n < 4; ++n)
      bf[n] = *reinterpret_cast<const f16x8*>(&Bs[buf][wc * 64 + n * 16 + lq][lk * 8]);
#pragma unroll
    for (int m = 0; m < 4; ++m)
#pragma unroll
      for (int n = 0; n < 4; ++n)
        acc[m][n] = __builtin_amdgcn_mfma_f32_16x16x32_f16(af[m], bf[n], acc[m][n], 0, 0, 0);
  }

  if (EPI == 0) {
#pragma unroll
    for (int m = 0; m < 4; ++m) {
#pragma unroll
      for (int j = 0; j < 4; ++j) {
        int row = brow + wr * 64 + m * 16 + lk * 4 + j;
        if (MB && row >= M) continue;
        float* dst = C + (size_t)row * N + bcol + wc * 64 + lq;
#pragma unroll
        for (int n = 0; n < 4; ++n) dst[n * 16] = acc[m][n][j];
      }
    }
  } else {
    // fused RMS over the 128-col head row (block spans exactly one head)
    __syncthreads();                          // LDS reuse fence
    float* ssq = (float*)(&As[0][0][0]);      // [128][2] partial sums
#pragma unroll
    for (int m = 0; m < 4; ++m)
#pragma unroll
      for (int j = 0; j < 4; ++j) {
        int lr = wr * 64 + m * 16 + lk * 4 + j;
        float pp = 0.f;
#pragma unroll
        for (int n = 0; n < 4; ++n) pp += acc[m][n][j] * acc[m][n][j];
        pp += __shfl_xor(pp, 1);
        pp += __shfl_xor(pp, 2);
        pp += __shfl_xor(pp, 4);
        pp += __shfl_xor(pp, 8);
        if (lq == 0) ssq[lr * 2 + wc] = pp;
      }
    __syncthreads();
    float wv[4];
#pragma unroll
    for (int n = 0; n < 4; ++n) wv[n] = wvec[wc * 64 + n * 16 + lq];
#pragma unroll
    for (int m = 0; m < 4; ++m)
#pragma unroll
      for (int j = 0; j < 4; ++j) {
        int lr = wr * 64 + m * 16 + lk * 4 + j;
        float ss = ssq[lr * 2] + ssq[lr * 2 + 1];
        float rs = rsqrtf(ss * (1.0f / 128.0f) + 1e-5f) *
                   (0.08838834764831845f * 1.4426950408889634f);
        f16* dst = Ch + (size_t)(brow + lr) * N + bcol + wc * 64 + lq;
#pragma unroll
        for (int n = 0; n < 4; ++n) dst[n * 16] = (f16)(acc[m][n][j] * rs * wv[n]);
      }
  }
}

// ---------------------------------------------------------------- K RMS-norm + V transpose scatter
// KVraw [6404][2048] fp32 -> Kf [b][kvh][1664][128] f16 (normed), Vtf [b][kvh][128][1664] f16
__global__ __launch_bounds__(256) void kvscatter_kernel(const float* __restrict__ KVraw,
                                                        const float* __restrict__ wk,
                                                        f16* __restrict__ Kf,
                                                        f16* __restrict__ Vtf) {
  const int w = threadIdx.x >> 6, l = threadIdx.x & 63;
  const int gw = blockIdx.x * 4 + w;  // 0..51231
  const int r = gw >> 3, kvh = gw & 7;
  const int b = r / 1601, s = r - b * 1601;
  const float* kr = KVraw + (size_t)r * 2048 + kvh * 128;
  float2 kx = reinterpret_cast<const float2*>(kr)[l];
  float ss = wave_sum64(kx.x * kx.x + kx.y * kx.y);
  float rs = rsqrtf(ss * (1.0f / 128.0f) + 1e-5f);
  float2 wv = reinterpret_cast<const float2*>(wk)[l];
  union { f16 h[2]; unsigned u; } pk;
  pk.h[0] = (f16)(kx.x * rs * wv.x);
  pk.h[1] = (f16)(kx.y * rs * wv.y);
  reinterpret_cast<unsigned*>(Kf + ((size_t)(b * 8 + kvh) * 1664 + s) * 128)[l] = pk.u;
  const float* vr = kr + 1024;
  float2 vx = reinterpret_cast<const float2*>(vr)[l];
  f16* vcol = Vtf + ((size_t)(b * 8 + kvh) * 128 + l * 2) * 1664 + s;
  vcol[0] = (f16)vx.x;
  vcol[1664] = (f16)vx.y;
}

// ---------------------------------------------------------------- flash attention (KVBLK=128, 64 KB LDS)
// Q [4096][4096] f16 (scale*log2e folded), Kf [b][kvh][1664][128], Vtf [b][kvh][128][1664]
// Oa [4096][4096] f16.  1-D grid of 1024 blocks, XCD-swizzled; 4 waves x 32 q rows.
// (256,2): 128-VGPR-class cap; (256,4)'s 64-cap spilled 2.8 GB/dispatch (round-3).
__global__ __launch_bounds__(256, 2) void attn_kernel(const f16* __restrict__ Qf,
                                                      const f16* __restrict__ Kf,
                                                      const f16* __restrict__ Vtf,
                                                      f16* __restrict__ Oa) {
  __shared__ f16 Ksm[128][128];  // 32 KB, rows 256 B, XOR-swizzled; P alias after QK^T
  __shared__ f16 Vsm[128][128];  // 32 KB, V^T tile [d][kv]
  const int p = blockIdx.x;              // 0..1023
  const int L = (p & 7) * 128 + (p >> 3);
  const int qt = L & 7, h = (L >> 3) & 31, b = L >> 8;
  const int kvh = h >> 2;  // G = 4
  const int tid = threadIdx.x;
  const int l = tid & 63, w = tid >> 6;
  const int lq = l & 15, lk = l >> 4;

  // Q fragments in registers (reused across all 13 KV tiles)
  f16x8 qreg[2][4];
  const f16* Qbase = Qf + ((size_t)(b * 1024 + qt * 128 + w * 32)) * 4096 + h * 128;
#pragma unroll
  for (int qm = 0; qm < 2; ++qm)
#pragma unroll
    for (int ks = 0; ks < 4; ++ks)
      qreg[qm][ks] = *reinterpret_cast<const f16x8*>(
          Qbase + (size_t)(qm * 16 + lq) * 4096 + ks * 32 + lk * 8);

  const f16* Kb = Kf + (size_t)(b * 8 + kvh) * (1664 * 128);
  const f16* Vb = Vtf + (size_t)(b * 8 + kvh) * (128 * 1664);

  f32x4 o[2][8];
  f32x4 zf = {0.f, 0.f, 0.f, 0.f};
#pragma unroll
  for (int qm = 0; qm < 2; ++qm)
#pragma unroll
    for (int dn = 0; dn < 8; ++dn) o[qm][dn] = zf;
  float mrow[2][4], lrow[2][4];  // lrow = per-lane PARTIAL row sum (reduced in epilogue)
#pragma unroll
  for (int qm = 0; qm < 2; ++qm)
#pragma unroll
    for (int j = 0; j < 4; ++j) { mrow[qm][j] = -1e30f; lrow[qm][j] = 0.f; }

  char* Pw = (char*)(&Ksm[0][0]) + w * 8192;  // per-wave 32q x 128kv alias of Ksm
  const int swzR = (lq & 7) << 4;

  for (int t = 0; t < 13; ++t) {
    // ---- stage K tile [128][128] (rows 256 B; 1 issue = 1024 B = 4 rows)
#pragma unroll
    for (int i = 0; i < 8; ++i) {
      int row = w * 32 + i * 4 + lk;
      int cb = (lq * 16) ^ ((row & 7) << 4);
      gload_lds16(Kb + (size_t)(t * 128 + row) * 128 + (cb >> 1),
                  (char*)(&Ksm[0][0]) + w * 8192 + i * 1024);
    }
    // ---- stage V^T tile [128][128]
#pragma unroll
    for (int i = 0; i < 8; ++i) {
      int r = w * 32 + i * 4 + lk;
      int cb = (lq * 16) ^ ((r & 7) << 4);
      gload_lds16(Vb + (size_t)r * 1664 + t * 128 + (cb >> 1),
                  (char*)(&Vsm[0][0]) + w * 8192 + i * 1024);
    }
    __syncthreads();

    // ---- S = Q K^T (fp32 accum), wave's 32 q rows x 128 kv cols
    f32x4 s[2][8];
#pragma unroll
    for (int qm = 0; qm < 2; ++qm)
#pragma unroll
      for (int kn = 0; kn < 8; ++kn) s[qm][kn] = zf;
    __builtin_amdgcn_s_setprio(1);
#pragma unroll
    for (int ks = 0; ks < 4; ++ks) {
      f16x8 bf[8];
#pragma unroll
      for (int kn = 0; kn < 8; ++kn)
        bf[kn] = *reinterpret_cast<const f16x8*>(
            (char*)(&Ksm[0][0]) + (kn * 16 + lq) * 256 + ((ks * 64 + lk * 16) ^ swzR));
#pragma unroll
      for (int qm = 0; qm < 2; ++qm)
#pragma unroll
        for (int kn = 0; kn < 8; ++kn)
          s[qm][kn] = __builtin_amdgcn_mfma_f32_16x16x32_f16(qreg[qm][ks], bf[kn], s[qm][kn], 0, 0, 0);
    }
    __builtin_amdgcn_s_setprio(0);
    __syncthreads();  // all waves' Ksm reads done -> Ksm reusable as P

    // ---- mask tail (valid kv < 1601; tile 12 covers 1536..1663 -> local < 65)
    if (t == 12) {
#pragma unroll
      for (int kn = 0; kn < 8; ++kn) {
        bool valid = (kn * 16 + lq) < 65;
#pragma unroll
        for (int qm = 0; qm < 2; ++qm)
#pragma unroll
          for (int j = 0; j < 4; ++j) s[qm][kn][j] = valid ? s[qm][kn][j] : -1e30f;
      }
    }

    // ---- online softmax (log2 domain), defer-rescale THR=8, per-lane lrow partials
#pragma unroll
    for (int qm = 0; qm < 2; ++qm) {
#pragma unroll
      for (int j = 0; j < 4; ++j) {
        float mt = s[qm][0][j];
#pragma unroll
        for (int kn = 1; kn < 8; ++kn) mt = fmaxf(mt, s[qm][kn][j]);
        mt = fmaxf(mt, __shfl_xor(mt, 1));
        mt = fmaxf(mt, __shfl_xor(mt, 2));
        mt = fmaxf(mt, __shfl_xor(mt, 4));
        mt = fmaxf(mt, __shfl_xor(mt, 8));
        float mo = mrow[qm][j];
        if (mt > mo + 8.0f) {           // rarely taken after tile 0
          float corr = exp2f(mo - mt);
          mrow[qm][j] = mt;
          lrow[qm][j] *= corr;
#pragma unroll
          for (int dn = 0; dn < 8; ++dn) o[qm][dn][j] *= corr;
          mo = mt;
        }
        float rsum = 0.f;
#pragma unroll
        for (int kn = 0; kn < 8; ++kn) {
          float pv = exp2f(s[qm][kn][j] - mo);
          s[qm][kn][j] = pv;
          rsum += pv;
        }
        lrow[qm][j] += rsum;            // per-lane partial; no shfl here
        int prow = qm * 16 + lk * 4 + j;
        int swzW = (prow & 7) << 4;
#pragma unroll
        for (int kn = 0; kn < 8; ++kn)
          *reinterpret_cast<f16*>(Pw + prow * 256 + (((kn * 16 + lq) * 2) ^ swzW)) =
              (f16)s[qm][kn][j];
      }
    }

    // ---- O += P V   (A = P from Ksm alias, B = V^T from Vsm, both swizzled b128)
    __builtin_amdgcn_s_setprio(1);
#pragma unroll
    for (int ks = 0; ks < 4; ++ks) {
      f16x8 pa[2];
#pragma unroll
      for (int qm = 0; qm < 2; ++qm)
        pa[qm] = *reinterpret_cast<const f16x8*>(
            Pw + (qm * 16 + lq) * 256 + ((ks * 64 + lk * 16) ^ swzR));
      f16x8 vb[8];
#pragma unroll
      for (int dn = 0; dn < 8; ++dn)
        vb[dn] = *reinterpret_cast<const f16x8*>(
            (char*)(&Vsm[0][0]) + (dn * 16 + lq) * 256 + ((ks * 64 + lk * 16) ^ swzR));
#pragma unroll
      for (int qm = 0; qm < 2; ++qm)
#pragma unroll
        for (int dn = 0; dn < 8; ++dn)
          o[qm][dn] = __builtin_amdgcn_mfma_f32_16x16x32_f16(pa[qm], vb[dn], o[qm][dn], 0, 0, 0);
    }
    __builtin_amdgcn_s_setprio(0);
    __syncthreads();  // P/V reads done before next tile's staging overwrites
  }

  // ---- epilogue: reduce lrow partials across the 16-lane row group, then O/l
#pragma unroll
  for (int qm = 0; qm < 2; ++qm) {
#pragma unroll
    for (int j = 0; j < 4; ++j) {
      float fl = lrow[qm][j];
      fl += __shfl_xor(fl, 1);
      fl += __shfl_xor(fl, 2);
      fl += __shfl_xor(fl, 4);
      fl += __shfl_xor(fl, 8);
      float il = 1.0f / fl;
      int token = b * 1024 + qt * 128 + w * 32 + qm * 16 + lk * 4 + j;
      f16* dst = Oa + (size_t)token * 4096 + h * 128;
#pragma unroll
      for (int dn = 0; dn < 8; ++dn) dst[dn * 16 + lq] = (f16)(o[qm][dn][j] * il);
    }
  }
}

// ---------------------------------------------------------------- launch
extern "C" void kernel_launch(void* const* d_in, const int* in_sizes, int n_in,
                              void* d_out, int out_size, void* d_ws, size_t ws_size,
                              hipStream_t stream) {
  const float* hidden = (const float*)d_in[0];  // [4,1024,4096]
  const float* cross  = (const float*)d_in[1];  // [4,1601,4096]
  const float* wqkv   = (const float*)d_in[2];  // [6144,4096]
  const float* wo     = (const float*)d_in[3];  // [4096,4096]
  const float* qw     = (const float*)d_in[4];  // [128]
  const float* kw     = (const float*)d_in[5];  // [128]

  char* ws = (char*)d_ws;
  // region A: hidden_f16 (33.55 MB) -> later attn_f16
  f16* hidden_h = (f16*)(ws + 0);
  f16* attn_h   = hidden_h;
  // region B: wqkv_f16 (50.33 MB)
  f16* wqkv_h = (f16*)(ws + 33554432);
  // region C: cross_f16 (52.46 MB) -> later K_f16 (13.63) + Vt_f16 (13.63)
  f16* cross_h = (f16*)(ws + 83886080);
  f16* k_h     = cross_h;
  f16* vt_h    = (f16*)(ws + 83886080 + 13631488);
  // region D: KVraw fp32 (52.46 MB) -> later wo_f16
  float* kvraw = (float*)(ws + 136347648);
  f16* wo_h    = (f16*)(ws + 136347648);
  // total ws use: 188,809,216 B
  // q_h lives in d_out (f16, 33.5 MB of the 67 MB fp32 buffer); it is fully
  // consumed by attn before the O-projection overwrites d_out.
  f16* q_h = (f16*)d_out;

  // 1) converts needed before projections
  cvt_kernel<<<2048, 256, 0, stream>>>(hidden, hidden_h, 16777216 / 4);
  cvt_kernel<<<2048, 256, 0, stream>>>(cross, cross_h, 26230784 / 4);
  cvt_kernel<<<2048, 256, 0, stream>>>(wqkv, wqkv_h, 25165824 / 4);
  // 2) KV projection: cross @ wqkv[4096:6144]^T -> KVraw [6404][2048]
  gemm_bt_f16<true, 0><<<dim3(16, 51), 256, 0, stream>>>(
      cross_h, wqkv_h + (size_t)4096 * 4096, kvraw, nullptr, nullptr, 6404, 2048, 4096);
  // 3) zero K/Vt pad cols (s in [1601,1664)), then scatter K (rms) + V (transpose)
  hipMemsetAsync(ws + 83886080, 0, 27262976, stream);
  kvscatter_kernel<<<12808, 256, 0, stream>>>(kvraw, kw, k_h, vt_h);
  // 4) wo convert (into dead KVraw region)
  cvt_kernel<<<2048, 256, 0, stream>>>(wo, wo_h, 16777216 / 4);
  // 5) Q projection with fused RMS-norm (+scale*log2e) -> f16 q_h (in d_out)
  gemm_bt_f16<false, 1><<<dim3(32, 32), 256, 0, stream>>>(
      hidden_h, wqkv_h, nullptr, q_h, qw, 4096, 4096, 4096);
  // 6) attention (1-D grid, XCD-swizzled in-kernel)
  attn_kernel<<<1024, 256, 0, stream>>>(q_h, k_h, vt_h, attn_h);
  // 7) output projection -> d_out
  gemm_bt_f16<false, 0><<<dim3(32, 32), 256, 0, stream>>>(
      attn_h, wo_h, (float*)d_out, nullptr, nullptr, 4096, 4096, 4096);
}

// Round 6
// 845.999 us; speedup vs baseline: 1.3668x; 1.3668x over previous
//
#include <hip/hip_runtime.h>
#include <cstdint>
#include <math.h>

typedef _Float16 f16;
typedef __attribute__((ext_vector_type(4))) _Float16 f16x4;
typedef __attribute__((ext_vector_type(8))) _Float16 f16x8;
typedef __attribute__((ext_vector_type(4))) float f32x4;

// ---------------------------------------------------------------- helpers
__device__ inline void gload_lds16(const void* g, void* l) {
  auto gp = reinterpret_cast<const __attribute__((address_space(1))) uint32_t*>(
      reinterpret_cast<uintptr_t>(g));
  auto lp = reinterpret_cast<__attribute__((address_space(3))) uint32_t*>(
      reinterpret_cast<uintptr_t>(l));
  __builtin_amdgcn_global_load_lds(gp, lp, 16 /*bytes*/, 0, 0);
}

__device__ inline float wave_sum64(float v) {
#pragma unroll
  for (int m = 1; m < 64; m <<= 1) v += __shfl_xor(v, m);
  return v;
}

// ---------------------------------------------------------------- fp32 -> f16 convert
__global__ __launch_bounds__(256) void cvt_kernel(const float* __restrict__ src,
                                                  f16* __restrict__ dst, int n4) {
  int idx = blockIdx.x * blockDim.x + threadIdx.x;
  int stride = gridDim.x * blockDim.x;
  for (int i = idx; i < n4; i += stride) {
    float4 v = reinterpret_cast<const float4*>(src)[i];
    f16x4 h;
    h.x = (f16)v.x; h.y = (f16)v.y; h.z = (f16)v.z; h.w = (f16)v.w;
    reinterpret_cast<f16x4*>(dst)[i] = h;
  }
}

// ---------------------------------------------------------------- GEMM  C[M][N] = A[M][K] * B[N][K]^T
// 128x128 tile, BK=32, 4 waves (each a 64x64 quadrant), m97 structure + XCD swizzle.
// EPI==0: plain fp32 C.  EPI==1: fused RMS-norm (per 128-col head row) -> f16 Ch,
// with attention scale * log2e folded (Q path).
template <bool MB, int EPI>
__global__ __launch_bounds__(256, 2) void gemm_bt_f16(const f16* __restrict__ A,
                                                      const f16* __restrict__ Bw,
                                                      float* __restrict__ C,
                                                      f16* __restrict__ Ch,
                                                      const float* __restrict__ wvec,
                                                      int M, int N, int K) {
  __shared__ f16 As[2][128][32];
  __shared__ f16 Bs[2][128][32];
  const int tid = threadIdx.x;
  const int l = tid & 63, w = tid >> 6;
  const int lq = l & 15, lk = l >> 4;
  const int wr = w >> 1, wc = w & 1;
  // XCD-aware bijective swizzle (nwg % 8 == 0 for all our grids)
  const int nwg = gridDim.x * gridDim.y;
  const int p = blockIdx.y * gridDim.x + blockIdx.x;
  const int L = (p & 7) * (nwg >> 3) + (p >> 3);
  const int bx = L % gridDim.x, by = L / gridDim.x;
  const int brow = by * 128, bcol = bx * 128;
  const int srow = w * 16 + (l >> 2);   // staging row (+j*64)
  const int scol = (l & 3) * 8;         // staging col in f16 elems
  const int KT = K >> 5;

  f32x4 acc[4][4];
  f32x4 zf = {0.f, 0.f, 0.f, 0.f};
#pragma unroll
  for (int m = 0; m < 4; ++m)
#pragma unroll
    for (int n = 0; n < 4; ++n) acc[m][n] = zf;

  auto stage = [&](int kt, int buf) {
    const int k0 = kt * 32 + scol;
#pragma unroll
    for (int j = 0; j < 2; ++j) {
      int ra = brow + j * 64 + srow;
      if (MB) ra = (ra < M) ? ra : (M - 1);
      gload_lds16(A + (size_t)ra * K + k0,
                  (char*)(&As[buf][0][0]) + j * 4096 + w * 1024);
      int rb = bcol + j * 64 + srow;
      gload_lds16(Bw + (size_t)rb * K + k0,
                  (char*)(&Bs[buf][0][0]) + j * 4096 + w * 1024);
    }
  };

  stage(0, 0);
  for (int kt = 0; kt < KT; ++kt) {
    const int buf = kt & 1;
    __syncthreads();                 // drains vmcnt for stage(kt); also read/overwrite fence
    if (kt + 1 < KT) stage(kt + 1, buf ^ 1);  // prefetch overlaps this iter's compute
    f16x8 af[4], bf[4];
#pragma unroll
    for (int m = 0; m < 4; ++m)
      af[m] = *reinterpret_cast<const f16x8*>(&As[buf][wr * 64 + m * 16 + lq][lk * 8]);
#pragma unroll
    for (int n = 0; n < 4; ++n)
      bf[n] = *reinterpret_cast<const f16x8*>(&Bs[buf][wc * 64 + n * 16 + lq][lk * 8]);
#pragma unroll
    for (int m = 0; m < 4; ++m)
#pragma unroll
      for (int n = 0; n < 4; ++n)
        acc[m][n] = __builtin_amdgcn_mfma_f32_16x16x32_f16(af[m], bf[n], acc[m][n], 0, 0, 0);
  }

  if (EPI == 0) {
#pragma unroll
    for (int m = 0; m < 4; ++m) {
#pragma unroll
      for (int j = 0; j < 4; ++j) {
        int row = brow + wr * 64 + m * 16 + lk * 4 + j;
        if (MB && row >= M) continue;
        float* dst = C + (size_t)row * N + bcol + wc * 64 + lq;
#pragma unroll
        for (int n = 0; n < 4; ++n) dst[n * 16] = acc[m][n][j];
      }
    }
  } else {
    // fused RMS over the 128-col head row (block spans exactly one head)
    __syncthreads();                          // LDS reuse fence
    float* ssq = (float*)(&As[0][0][0]);      // [128][2] partial sums
#pragma unroll
    for (int m = 0; m < 4; ++m)
#pragma unroll
      for (int j = 0; j < 4; ++j) {
        int lr = wr * 64 + m * 16 + lk * 4 + j;
        float pp = 0.f;
#pragma unroll
        for (int n = 0; n < 4; ++n) pp += acc[m][n][j] * acc[m][n][j];
        pp += __shfl_xor(pp, 1);
        pp += __shfl_xor(pp, 2);
        pp += __shfl_xor(pp, 4);
        pp += __shfl_xor(pp, 8);
        if (lq == 0) ssq[lr * 2 + wc] = pp;
      }
    __syncthreads();
    float wv[4];
#pragma unroll
    for (int n = 0; n < 4; ++n) wv[n] = wvec[wc * 64 + n * 16 + lq];
#pragma unroll
    for (int m = 0; m < 4; ++m)
#pragma unroll
      for (int j = 0; j < 4; ++j) {
        int lr = wr * 64 + m * 16 + lk * 4 + j;
        float ss = ssq[lr * 2] + ssq[lr * 2 + 1];
        float rs = rsqrtf(ss * (1.0f / 128.0f) + 1e-5f) *
                   (0.08838834764831845f * 1.4426950408889634f);
        f16* dst = Ch + (size_t)(brow + lr) * N + bcol + wc * 64 + lq;
#pragma unroll
        for (int n = 0; n < 4; ++n) dst[n * 16] = (f16)(acc[m][n][j] * rs * wv[n]);
      }
  }
}

// ---------------------------------------------------------------- K RMS-norm + V transpose scatter
// KVraw [6404][2048] fp32 -> Kf [b][kvh][1664][128] f16 (normed), Vtf [b][kvh][128][1664] f16
__global__ __launch_bounds__(256) void kvscatter_kernel(const float* __restrict__ KVraw,
                                                        const float* __restrict__ wk,
                                                        f16* __restrict__ Kf,
                                                        f16* __restrict__ Vtf) {
  const int w = threadIdx.x >> 6, l = threadIdx.x & 63;
  const int gw = blockIdx.x * 4 + w;  // 0..51231
  const int r = gw >> 3, kvh = gw & 7;
  const int b = r / 1601, s = r - b * 1601;
  const float* kr = KVraw + (size_t)r * 2048 + kvh * 128;
  float2 kx = reinterpret_cast<const float2*>(kr)[l];
  float ss = wave_sum64(kx.x * kx.x + kx.y * kx.y);
  float rs = rsqrtf(ss * (1.0f / 128.0f) + 1e-5f);
  float2 wv = reinterpret_cast<const float2*>(wk)[l];
  union { f16 h[2]; unsigned u; } pk;
  pk.h[0] = (f16)(kx.x * rs * wv.x);
  pk.h[1] = (f16)(kx.y * rs * wv.y);
  reinterpret_cast<unsigned*>(Kf + ((size_t)(b * 8 + kvh) * 1664 + s) * 128)[l] = pk.u;
  const float* vr = kr + 1024;
  float2 vx = reinterpret_cast<const float2*>(vr)[l];
  f16* vcol = Vtf + ((size_t)(b * 8 + kvh) * 128 + l * 2) * 1664 + s;
  vcol[0] = (f16)vx.x;
  vcol[1664] = (f16)vx.y;
}

// ---------------------------------------------------------------- flash attention
// KVBLK=64, K/V double-buffered + separate per-wave P: 80 KB LDS, 2 blocks/CU.
// Raw s_barrier + counted vmcnt(8) keeps next tile's 8 gload_lds in flight across
// the barrier (no __syncthreads drain). 2 barriers/tile, none draining prefetch.
// (256,2): 128-VGPR class; s[2][4] keeps live state under the cap (r3/r5 lessons).
__global__ __launch_bounds__(256, 2) void attn_kernel(const f16* __restrict__ Qf,
                                                      const f16* __restrict__ Kf,
                                                      const f16* __restrict__ Vtf,
                                                      f16* __restrict__ Oa) {
  __shared__ f16 Ksm[2][64][128];  // 32 KB dbuf, 256 B rows, XOR-swizzled
  __shared__ f16 Vsm[2][128][64];  // 32 KB dbuf, V^T [d][kv], 128 B rows, swizzled
  __shared__ f16 Psm[4][32][64];   // 16 KB per-wave P (wave-private, no cross-wave sync)
  const int p = blockIdx.x;              // 0..1023
  const int L = (p & 7) * 128 + (p >> 3);
  const int qt = L & 7, h = (L >> 3) & 31, b = L >> 8;
  const int kvh = h >> 2;  // G = 4
  const int tid = threadIdx.x;
  const int l = tid & 63, w = tid >> 6;
  const int lq = l & 15, lk = l >> 4;

  // Q fragments in registers (reused across all 26 KV tiles)
  f16x8 qreg[2][4];
  const f16* Qbase = Qf + ((size_t)(b * 1024 + qt * 128 + w * 32)) * 4096 + h * 128;
#pragma unroll
  for (int qm = 0; qm < 2; ++qm)
#pragma unroll
    for (int ks = 0; ks < 4; ++ks)
      qreg[qm][ks] = *reinterpret_cast<const f16x8*>(
          Qbase + (size_t)(qm * 16 + lq) * 4096 + ks * 32 + lk * 8);

  const f16* Kb = Kf + (size_t)(b * 8 + kvh) * (1664 * 128);
  const f16* Vb = Vtf + (size_t)(b * 8 + kvh) * (128 * 1664);

  f32x4 o[2][8];
  f32x4 zf = {0.f, 0.f, 0.f, 0.f};
#pragma unroll
  for (int qm = 0; qm < 2; ++qm)
#pragma unroll
    for (int dn = 0; dn < 8; ++dn) o[qm][dn] = zf;
  float mrow[2][4], lrow[2][4];  // lrow = per-lane PARTIAL sums, reduced in epilogue
#pragma unroll
  for (int qm = 0; qm < 2; ++qm)
#pragma unroll
    for (int j = 0; j < 4; ++j) { mrow[qm][j] = -1e30f; lrow[qm][j] = 0.f; }

  char* Pw = (char*)(&Psm[w][0][0]);
  const int swzR = (lq & 7) << 4;

  auto stageK = [&](int t, int buf) {
#pragma unroll
    for (int i = 0; i < 4; ++i) {
      int row = w * 16 + i * 4 + lk;
      int cb = (lq * 16) ^ ((row & 7) << 4);
      gload_lds16(Kb + (size_t)(t * 64 + row) * 128 + (cb >> 1),
                  (char*)(&Ksm[buf][0][0]) + w * 4096 + i * 1024);
    }
  };
  auto stageV = [&](int t, int buf) {
#pragma unroll
    for (int i = 0; i < 4; ++i) {
      int r = w * 32 + i * 8 + (l >> 3);
      int cb = ((l & 7) * 16) ^ ((r & 7) << 4);
      gload_lds16(Vb + (size_t)r * 1664 + t * 64 + (cb >> 1),
                  (char*)(&Vsm[buf][0][0]) + w * 4096 + i * 1024);
    }
  };

  stageK(0, 0);
  stageV(0, 0);
  int cur = 0;
  for (int t = 0; t < 26; ++t) {
    if (t < 25) {
      stageK(t + 1, cur ^ 1);                       // 8 issues for tile t+1 in flight
      stageV(t + 1, cur ^ 1);
      asm volatile("s_waitcnt vmcnt(8)" ::: "memory");  // own tile-t loads done
    } else {
      asm volatile("s_waitcnt vmcnt(0)" ::: "memory");
    }
    __builtin_amdgcn_s_barrier();                   // all waves' tile-t loads done

    // ---- S = Q K^T (fp32 accum), wave's 32 q rows x 64 kv cols
    f32x4 s[2][4];
#pragma unroll
    for (int qm = 0; qm < 2; ++qm)
#pragma unroll
      for (int kn = 0; kn < 4; ++kn) s[qm][kn] = zf;
    __builtin_amdgcn_s_setprio(1);
#pragma unroll
    for (int ks = 0; ks < 4; ++ks) {
      f16x8 bf[4];
#pragma unroll
      for (int kn = 0; kn < 4; ++kn)
        bf[kn] = *reinterpret_cast<const f16x8*>(
            (char*)(&Ksm[cur][0][0]) + (kn * 16 + lq) * 256 + ((ks * 64 + lk * 16) ^ swzR));
#pragma unroll
      for (int qm = 0; qm < 2; ++qm)
#pragma unroll
        for (int kn = 0; kn < 4; ++kn)
          s[qm][kn] = __builtin_amdgcn_mfma_f32_16x16x32_f16(qreg[qm][ks], bf[kn], s[qm][kn], 0, 0, 0);
    }
    __builtin_amdgcn_s_setprio(0);

    // ---- mask tail (valid kv < 1601; tile 25 covers 1600..1663 -> local < 1)
    if (t == 25) {
#pragma unroll
      for (int kn = 0; kn < 4; ++kn) {
        bool valid = (kn * 16 + lq) < 1;
#pragma unroll
        for (int qm = 0; qm < 2; ++qm)
#pragma unroll
          for (int j = 0; j < 4; ++j) s[qm][kn][j] = valid ? s[qm][kn][j] : -1e30f;
      }
    }

    // ---- online softmax (log2 domain), defer-rescale THR=8, per-lane lrow partials
#pragma unroll
    for (int qm = 0; qm < 2; ++qm) {
#pragma unroll
      for (int j = 0; j < 4; ++j) {
        float mt = fmaxf(fmaxf(s[qm][0][j], s[qm][1][j]), fmaxf(s[qm][2][j], s[qm][3][j]));
        mt = fmaxf(mt, __shfl_xor(mt, 1));
        mt = fmaxf(mt, __shfl_xor(mt, 2));
        mt = fmaxf(mt, __shfl_xor(mt, 4));
        mt = fmaxf(mt, __shfl_xor(mt, 8));
        float mo = mrow[qm][j];
        if (mt > mo + 8.0f) {           // rarely taken after tile 0
          float corr = exp2f(mo - mt);
          mrow[qm][j] = mt;
          lrow[qm][j] *= corr;
#pragma unroll
          for (int dn = 0; dn < 8; ++dn) o[qm][dn][j] *= corr;
          mo = mt;
        }
        float rsum = 0.f;
#pragma unroll
        for (int kn = 0; kn < 4; ++kn) {
          float pv = exp2f(s[qm][kn][j] - mo);
          s[qm][kn][j] = pv;
          rsum += pv;
        }
        lrow[qm][j] += rsum;            // per-lane partial; no shfl here
        int prow = qm * 16 + lk * 4 + j;
        int swzW = (prow & 7) << 4;
#pragma unroll
        for (int kn = 0; kn < 4; ++kn)
          *reinterpret_cast<f16*>(Pw + prow * 128 + (((kn * 16 + lq) * 2) ^ swzW)) =
              (f16)s[qm][kn][j];
      }
    }

    // ---- O += P V   (A = P from own Psm, B = V^T from Vsm[cur], both swizzled b128)
    __builtin_amdgcn_s_setprio(1);
#pragma unroll
    for (int c = 0; c < 2; ++c) {
      f16x8 pa[2];
#pragma unroll
      for (int qm = 0; qm < 2; ++qm)
        pa[qm] = *reinterpret_cast<const f16x8*>(
            Pw + (qm * 16 + lq) * 128 + ((c * 64 + lk * 16) ^ swzR));
      f16x8 vb[8];
#pragma unroll
      for (int dn = 0; dn < 8; ++dn)
        vb[dn] = *reinterpret_cast<const f16x8*>(
            (char*)(&Vsm[cur][0][0]) + (dn * 16 + lq) * 128 + ((c * 64 + lk * 16) ^ swzR));
#pragma unroll
      for (int qm = 0; qm < 2; ++qm)
#pragma unroll
        for (int dn = 0; dn < 8; ++dn)
          o[qm][dn] = __builtin_amdgcn_mfma_f32_16x16x32_f16(pa[qm], vb[dn], o[qm][dn], 0, 0, 0);
    }
    __builtin_amdgcn_s_setprio(0);
    __builtin_amdgcn_s_barrier();   // all reads of buf `cur` done before next stage hits it
    cur ^= 1;
  }

  // ---- epilogue: reduce lrow partials across the 16-lane row group, then O/l
#pragma unroll
  for (int qm = 0; qm < 2; ++qm) {
#pragma unroll
    for (int j = 0; j < 4; ++j) {
      float fl = lrow[qm][j];
      fl += __shfl_xor(fl, 1);
      fl += __shfl_xor(fl, 2);
      fl += __shfl_xor(fl, 4);
      fl += __shfl_xor(fl, 8);
      float il = 1.0f / fl;
      int token = b * 1024 + qt * 128 + w * 32 + qm * 16 + lk * 4 + j;
      f16* dst = Oa + (size_t)token * 4096 + h * 128;
#pragma unroll
      for (int dn = 0; dn < 8; ++dn) dst[dn * 16 + lq] = (f16)(o[qm][dn][j] * il);
    }
  }
}

// ---------------------------------------------------------------- launch
extern "C" void kernel_launch(void* const* d_in, const int* in_sizes, int n_in,
                              void* d_out, int out_size, void* d_ws, size_t ws_size,
                              hipStream_t stream) {
  const float* hidden = (const float*)d_in[0];  // [4,1024,4096]
  const float* cross  = (const float*)d_in[1];  // [4,1601,4096]
  const float* wqkv   = (const float*)d_in[2];  // [6144,4096]
  const float* wo     = (const float*)d_in[3];  // [4096,4096]
  const float* qw     = (const float*)d_in[4];  // [128]
  const float* kw     = (const float*)d_in[5];  // [128]

  char* ws = (char*)d_ws;
  // region A: hidden_f16 (33.55 MB) -> later attn_f16
  f16* hidden_h = (f16*)(ws + 0);
  f16* attn_h   = hidden_h;
  // region B: wqkv_f16 (50.33 MB)
  f16* wqkv_h = (f16*)(ws + 33554432);
  // region C: cross_f16 (52.46 MB) -> later K_f16 (13.63) + Vt_f16 (13.63)
  f16* cross_h = (f16*)(ws + 83886080);
  f16* k_h     = cross_h;
  f16* vt_h    = (f16*)(ws + 83886080 + 13631488);
  // region D: KVraw fp32 (52.46 MB) -> later wo_f16
  float* kvraw = (float*)(ws + 136347648);
  f16* wo_h    = (f16*)(ws + 136347648);
  // total ws use: 188,809,216 B
  // q_h lives in d_out (f16, 33.5 MB of the 67 MB fp32 buffer); it is fully
  // consumed by attn before the O-projection overwrites d_out.
  f16* q_h = (f16*)d_out;

  // 1) converts needed before projections
  cvt_kernel<<<2048, 256, 0, stream>>>(hidden, hidden_h, 16777216 / 4);
  cvt_kernel<<<2048, 256, 0, stream>>>(cross, cross_h, 26230784 / 4);
  cvt_kernel<<<2048, 256, 0, stream>>>(wqkv, wqkv_h, 25165824 / 4);
  // 2) KV projection: cross @ wqkv[4096:6144]^T -> KVraw [6404][2048]
  gemm_bt_f16<true, 0><<<dim3(16, 51), 256, 0, stream>>>(
      cross_h, wqkv_h + (size_t)4096 * 4096, kvraw, nullptr, nullptr, 6404, 2048, 4096);
  // 3) zero K/Vt pad cols (s in [1601,1664)), then scatter K (rms) + V (transpose)
  hipMemsetAsync(ws + 83886080, 0, 27262976, stream);
  kvscatter_kernel<<<12808, 256, 0, stream>>>(kvraw, kw, k_h, vt_h);
  // 4) wo convert (into dead KVraw region)
  cvt_kernel<<<2048, 256, 0, stream>>>(wo, wo_h, 16777216 / 4);
  // 5) Q projection with fused RMS-norm (+scale*log2e) -> f16 q_h (in d_out)
  gemm_bt_f16<false, 1><<<dim3(32, 32), 256, 0, stream>>>(
      hidden_h, wqkv_h, nullptr, q_h, qw, 4096, 4096, 4096);
  // 6) attention (1-D grid, XCD-swizzled in-kernel)
  attn_kernel<<<1024, 256, 0, stream>>>(q_h, k_h, vt_h, attn_h);
  // 7) output projection -> d_out
  gemm_bt_f16<false, 0><<<dim3(32, 32), 256, 0, stream>>>(
      attn_h, wo_h, (float*)d_out, nullptr, nullptr, 4096, 4096, 4096);
}